// Round 7
// baseline (246.517 us; speedup 1.0000x reference)
//
#include <hip/hip_runtime.h>
#include <math.h>

#define EPS 1e-5f
#define T_LEN 8192
#define SEG 512                     // elements per segment = one wave's worth
#define SEGS_PER_ROW (T_LEN / SEG)  // 16

// ---- wave64 DPP inclusive-scan helpers (VALU only, no DS pipe) ----
template<int CTRL, int RM>
__device__ __forceinline__ float dpp_add(float x) {
    int sh = __builtin_amdgcn_update_dpp(0, __float_as_int(x),
                                         CTRL, RM, 0xF, false);
    return x + __int_as_float(sh);
}
__device__ __forceinline__ float wave64_incl_scan(float x) {
    x = dpp_add<0x111, 0xF>(x);   // row_shr:1
    x = dpp_add<0x112, 0xF>(x);   // row_shr:2
    x = dpp_add<0x114, 0xF>(x);   // row_shr:4
    x = dpp_add<0x118, 0xF>(x);   // row_shr:8
    x = dpp_add<0x142, 0xA>(x);   // row_bcast:15 -> rows 1,3
    x = dpp_add<0x143, 0xC>(x);   // row_bcast:31 -> rows 2,3
    return x;
}
__device__ __forceinline__ float rd63(float x) {
    return __int_as_float(__builtin_amdgcn_readlane(__float_as_int(x), 63));
}

// ===== Pass 1: per-row segment prefix sums =====
// Block = one row (1024 thr, 16 waves). Wave w covers segment w exactly
// (512 elems, 8/lane). Pure read stream + trivial reduce; writes 16
// exclusive-prefix (sum,sumsq) float2s per row.
__global__ __launch_bounds__(1024) void causal_ln_pass1(
    const float* __restrict__ x,
    float2* __restrict__ partial)
{
    __shared__ float2 wtot[SEGS_PER_ROW];

    const int t    = threadIdx.x;
    const int lane = t & 63;
    const int wid  = t >> 6;             // wave id == segment id
    const int row  = blockIdx.x;

    const float4* xg = (const float4*)(x + (long long)row * T_LEN);
    float4 a = xg[2 * t];
    float4 b = xg[2 * t + 1];

    float s  = a.x + a.y + a.z + a.w + b.x + b.y + b.z + b.w;
    float s2 = a.x*a.x + a.y*a.y + a.z*a.z + a.w*a.w
             + b.x*b.x + b.y*b.y + b.z*b.z + b.w*b.w;

    float ts  = rd63(wave64_incl_scan(s));    // segment totals
    float ts2 = rd63(wave64_incl_scan(s2));

    if (lane == 0) wtot[wid] = make_float2(ts, ts2);
    __syncthreads();

    if (t < SEGS_PER_ROW) {
        float p1 = 0.f, p2 = 0.f;
#pragma unroll
        for (int w = 0; w < SEGS_PER_ROW - 1; ++w) {
            if (w < t) { p1 += wtot[w].x; p2 += wtot[w].y; }
        }
        partial[row * SEGS_PER_ROW + t] = make_float2(p1, p2);
    }
}

// ===== Pass 2: wave-autonomous replay =====
// One wave = one 512-elem segment. No barriers, no LDS, no cross-wave
// coupling. 65536 independent waves, 4 per 256-thr block: short dependent
// chains + huge desynchronized wave population = streaming regime.
__global__ __launch_bounds__(256) void causal_ln_pass2(
    const float* __restrict__ x,
    const float2* __restrict__ partial,
    const float* __restrict__ weight,
    const float* __restrict__ bias,
    float* __restrict__ out,
    int C)
{
    const int t    = threadIdx.x;
    const int lane = t & 63;
    const int wid  = t >> 6;                      // 0..3
    const int seg  = blockIdx.x * 4 + wid;        // global segment id
    const int row  = seg >> 4;                    // /SEGS_PER_ROW
    const int w    = seg & (SEGS_PER_ROW - 1);

    const float2 pre = partial[seg];              // exclusive row prefix
    const float  wv  = weight[row % C];
    const float  bv  = bias[row % C];

    const float4* xg = (const float4*)(x + (long long)row * T_LEN + w * SEG);
    float4 a = xg[2 * lane];
    float4 b = xg[2 * lane + 1];

    // data-independent 1/count table (under load shadow)
    const float cb = (float)(w * SEG + lane * 8);
    float rcv[8];
#pragma unroll
    for (int i = 0; i < 8; ++i)
        rcv[i] = __builtin_amdgcn_rcpf(cb + (float)(i + 1));

    float xs[8] = {a.x, a.y, a.z, a.w, b.x, b.y, b.z, b.w};

    float s = 0.f, s2 = 0.f;
#pragma unroll
    for (int i = 0; i < 8; ++i) { s += xs[i]; s2 += xs[i] * xs[i]; }

    float ws  = wave64_incl_scan(s);
    float ws2 = wave64_incl_scan(s2);

    float run  = pre.x + (ws  - s);               // exclusive prefix
    float run2 = pre.y + (ws2 - s2);

#pragma unroll
    for (int i = 0; i < 8; ++i) {
        float xi = xs[i];
        run  += xi;
        run2 += xi * xi;
        float mean = run * rcv[i];
        float var  = fmaxf(run2 * rcv[i] - mean * mean, 0.f);
        float rinv = __builtin_amdgcn_rsqf(var + EPS);
        xs[i] = (xi - mean) * rinv * wv + bv;
    }

    float4* og = (float4*)(out + (long long)row * T_LEN + w * SEG);
    og[2 * lane]     = make_float4(xs[0], xs[1], xs[2], xs[3]);
    og[2 * lane + 1] = make_float4(xs[4], xs[5], xs[6], xs[7]);
}

extern "C" void kernel_launch(void* const* d_in, const int* in_sizes, int n_in,
                              void* d_out, int out_size, void* d_ws, size_t ws_size,
                              hipStream_t stream) {
    const float* x      = (const float*)d_in[0];
    const float* weight = (const float*)d_in[1];
    const float* bias   = (const float*)d_in[2];
    float* out          = (float*)d_out;

    const int C = in_sizes[1];            // 512 (weight is [1,C,1])
    const int T = 8192;                   // time length per row
    const int rows = in_sizes[0] / T;     // B*C = 4096

    float2* partial = (float2*)d_ws;      // rows*16 float2 = 512 KB

    hipLaunchKernelGGL(causal_ln_pass1, dim3(rows), dim3(1024), 0, stream,
                       x, partial);
    hipLaunchKernelGGL(causal_ln_pass2, dim3(rows * SEGS_PER_ROW / 4),
                       dim3(256), 0, stream,
                       x, partial, weight, bias, out, C);
}